// Round 12
// baseline (171.975 us; speedup 1.0000x reference)
//
#include <hip/hip_runtime.h>
#include <math.h>

#define BB 8
#define NN 4096
#define MM 2048
#define CC 256
#define CBD 128

typedef __attribute__((ext_vector_type(8))) short s16x8;
typedef __attribute__((ext_vector_type(8))) _Float16 f16x8;
typedef __attribute__((ext_vector_type(4))) float f32x4;
typedef __attribute__((ext_vector_type(16))) float f32x16;
typedef unsigned short u16;
typedef unsigned int u32;

__device__ __forceinline__ u16 f2bf(float f) {
    union { float f; u32 u; } v; v.f = f;
    u32 r = v.u + 0x7fffu + ((v.u >> 16) & 1u);
    return (u16)(r >> 16);
}
__device__ __forceinline__ float bf2f(u16 h) {
    union { u32 u; float f; } v; v.u = ((u32)h) << 16; return v.f;
}
__device__ __forceinline__ u16 f2h(float f) {
    union { _Float16 h; u16 u; } v; v.h = (_Float16)f; return v.u;
}
__device__ __forceinline__ u32 asu(float f) {
    union { float f; u32 u; } v; v.f = f; return v.u;
}
// pack two f32 -> packed bf16 (truncate): low16 = lo, high16 = hi
__device__ __forceinline__ u32 pkbf(float lo, float hi) {
    return __builtin_amdgcn_perm(asu(hi), asu(lo), 0x07060302u);
}

#define MFMA(a, b, c)    __builtin_amdgcn_mfma_f32_16x16x32_bf16(a, b, c, 0, 0, 0)
#define MFMAF(a, b, c)   __builtin_amdgcn_mfma_f32_16x16x32_f16(a, b, c, 0, 0, 0)
#define MFMA32(a, b, c)  __builtin_amdgcn_mfma_f32_32x32x16_bf16(a, b, c, 0, 0, 0)
#define MFMA32F(a, b, c) __builtin_amdgcn_mfma_f32_32x32x16_f16(a, b, c, 0, 0, 0)

// --------------------------------------------- convert + transpose weights
// wt/wp/wg -> fp16 transposed [128][256]; wo -> bf16 transposed [256][128].
__global__ __launch_bounds__(256) void k_split_w(
    const float* __restrict__ wt, const float* __restrict__ wp,
    const float* __restrict__ wg, const float* __restrict__ wo,
    u16* wtf, u16* wpf, u16* wgf, u16* wot) {
    int e = blockIdx.x * 256 + threadIdx.x;
    int m = blockIdx.y;
    if (m < 3) {
        const float* src = m == 0 ? wt : (m == 1 ? wp : wg);
        u16* of = m == 0 ? wtf : (m == 1 ? wpf : wgf);
        int r = e >> 7, c = e & 127;          // src [256][128]
        of[c * 256 + r] = f2h(src[e]);
    } else {
        int r = e >> 8, c = e & 255;          // src [128][256]
        wot[c * 128 + r] = f2bf(wo[e]);
    }
}

// --------------------- single-pass fused theta/phi/g projection (fp16)
// (round-10 version, proven at the 159.0 best) One f16 MFMA pass per GEMM;
// kc+1 global loads prefetched into regs across the MFMA phase.
__global__ __launch_bounds__(256) void k_proj(
    const float* __restrict__ x,
    const u16* __restrict__ wtf, const u16* __restrict__ wpf,
    const u16* __restrict__ wgf,
    u16* __restrict__ th, u16* __restrict__ ph, u16* __restrict__ gt) {
    __shared__ u16 S[18176];                 // 36352 B
    const int THH = 0, PHH = 8704, GL = 13056;
    u16* sxf = S;
    u16* sw  = S + 2560;
    int tid = threadIdx.x;
    int w = tid >> 6, lane = tid & 63, q = lane >> 4, li = lane & 15;
    int r0 = blockIdx.x * 64;
    int wr2 = (w >> 1) * 32, wcc = (w & 1) * 64;
    const u16* Ws[3] = {wtf, wpf, wgf};

    f32x4 aT[2][4], aP[2][4], aG[2][4];
#pragma unroll
    for (int i = 0; i < 2; i++)
#pragma unroll
        for (int j = 0; j < 4; j++) {
            aT[i][j] = (f32x4)0.f; aP[i][j] = (f32x4)0.f; aG[i][j] = (f32x4)0.f;
        }

    int xrow = tid >> 2, xseg = tid & 3;
    const float* xbase = &x[(size_t)(r0 + xrow) * 256 + xseg * 8];
    int wcol = tid >> 2, wch = tid & 3;

    float4 cx0 = ((const float4*)xbase)[0];
    float4 cx1 = ((const float4*)xbase)[1];
    s16x8 cw[6];
#pragma unroll
    for (int u = 0; u < 6; u++)
        cw[u] = *(const s16x8*)&Ws[u >> 1][(size_t)((u & 1) * 64 + wcol) * 256 + wch * 8];

    for (int kc = 0; kc < 8; kc++) {
        {   // regs -> LDS (fp16 convert for x)
            u16 hh[8];
            hh[0] = f2h(cx0.x); hh[1] = f2h(cx0.y);
            hh[2] = f2h(cx0.z); hh[3] = f2h(cx0.w);
            hh[4] = f2h(cx1.x); hh[5] = f2h(cx1.y);
            hh[6] = f2h(cx1.z); hh[7] = f2h(cx1.w);
            *(s16x8*)&sxf[xrow * 40 + xseg * 8] = *(s16x8*)&hh[0];
#pragma unroll
            for (int u = 0; u < 6; u++)
                *(s16x8*)&sw[(u >> 1) * 5120 + ((u & 1) * 64 + wcol) * 40 + wch * 8] = cw[u];
        }
        __syncthreads();

        float4 nx0, nx1; s16x8 nw[6];
        if (kc < 7) {
            const float* xp = xbase + (kc + 1) * 32;
            nx0 = ((const float4*)xp)[0];
            nx1 = ((const float4*)xp)[1];
#pragma unroll
            for (int u = 0; u < 6; u++)
                nw[u] = *(const s16x8*)&Ws[u >> 1][(size_t)((u & 1) * 64 + wcol) * 256 +
                                                  (kc + 1) * 32 + wch * 8];
        }

        f16x8 af[2];
#pragma unroll
        for (int i = 0; i < 2; i++)
            af[i] = *(const f16x8*)&sxf[(wr2 + i * 16 + li) * 40 + q * 8];
#pragma unroll
        for (int j = 0; j < 4; j++) {
            int col = wcc + j * 16 + li;
            f16x8 bt = *(const f16x8*)&sw[0 * 5120 + col * 40 + q * 8];
            f16x8 bp = *(const f16x8*)&sw[1 * 5120 + col * 40 + q * 8];
            f16x8 bg = *(const f16x8*)&sw[2 * 5120 + col * 40 + q * 8];
#pragma unroll
            for (int i = 0; i < 2; i++) {
                aT[i][j] = MFMAF(af[i], bt, aT[i][j]);
                aP[i][j] = MFMAF(af[i], bp, aP[i][j]);
                aG[i][j] = MFMAF(af[i], bg, aG[i][j]);
            }
        }
        __syncthreads();
        if (kc < 7) {
            cx0 = nx0; cx1 = nx1;
#pragma unroll
            for (int u = 0; u < 6; u++) cw[u] = nw[u];
        }
    }

    // ---- epilogue: stage outputs in LDS, then coalesced stores ----
#pragma unroll
    for (int i = 0; i < 2; i++)
#pragma unroll
        for (int j = 0; j < 4; j++) {
            int col = wcc + j * 16 + li;
#pragma unroll
            for (int reg = 0; reg < 4; reg++) {   // theta -> fp16
                int row = wr2 + i * 16 + q * 4 + reg;
                S[THH + row * 136 + col] = f2h(aT[i][j][reg]);
            }
#pragma unroll
            for (int pr = 0; pr < 2; pr++) {      // pooled phi (fp16) / g (bf16)
                int ml = (wr2 >> 1) + i * 8 + q * 2 + pr;   // 0..31
                float vp = fmaxf(aP[i][j][pr * 2], aP[i][j][pr * 2 + 1]);
                S[PHH + ml * 136 + col] = f2h(vp);
                float vg = fmaxf(aG[i][j][pr * 2], aG[i][j][pr * 2 + 1]);
                int ml2 = (ml & ~12) | ((ml & 4) << 1) | ((ml & 8) >> 1);  // PV perm
                S[GL + col * 40 + ml2] = f2bf(vg);
            }
        }
    __syncthreads();

#pragma unroll
    for (int p2 = 0; p2 < 4; p2++) {
        int u2 = tid + p2 * 256;
        int row = u2 >> 4, chk = u2 & 15;
        size_t gb = (size_t)(r0 + row) * 128 + chk * 8;
        *(s16x8*)&th[gb] = *(const s16x8*)&S[THH + row * 136 + chk * 8];
    }
    {
        int row = tid >> 3, chk = tid & 7;
        size_t gb = (size_t)((r0 >> 1) + row) * 128 + chk * 16;
        *(s16x8*)&ph[gb]     = *(const s16x8*)&S[PHH + row * 136 + chk * 16];
        *(s16x8*)&ph[gb + 8] = *(const s16x8*)&S[PHH + row * 136 + chk * 16 + 8];
    }
    {
        int col = tid >> 1, half = tid & 1;
        int b = r0 >> 12;
        int base = (r0 >> 1) & 2047;              // multiple of 32
        size_t gb = (size_t)b * (128 * 2048) + (size_t)col * 2048 + base + half * 16;
        *(s16x8*)&gt[gb]     = *(const s16x8*)&S[GL + col * 40 + half * 16];
        *(s16x8*)&gt[gb + 8] = *(const s16x8*)&S[GL + col * 40 + half * 16 + 8];
    }
}

// --------------------- fused flash attention + output GEMM + residual
// No split-K: each block owns ALL 2048 keys for its 128 q-rows, so O is
// complete in-register -> exact 1/lrow normalization in-kernel, then the
// 128x256 W_out GEMM + residual run as an in-block epilogue (round-10
// k_out MFMA body). Eliminates k_out, ot (16MB w + 16MB r), Mv/Lv.
// Staging: register-prefetch double-buffer (k_proj's proven race-free
// pattern -- plain barriers, loads for tile t+1 issued under tile t's
// compute). 1-D grid 256, bb = bid&7 pins each batch's phi/g to one XCD.
// LDS 64 KB: main {skh 16K, sg 16K}; epilogue {sy 32K, sw 32K}.
__global__ __launch_bounds__(256) void k_attn(
    const u16* __restrict__ th, const u16* __restrict__ ph,
    const u16* __restrict__ gt, const u16* __restrict__ wot,
    const float* __restrict__ x, float* __restrict__ out) {
    __shared__ u16 smem[32768];          // 64 KB
    u16* skh = smem;                     // 64 keys x 128 ch fp16, swz chunk^=row&7
    u16* sg  = smem + 8192;              // 128 ch x 64 keys bf16, swz chunk^=row&7
    int tid = threadIdx.x, w = tid >> 6, lane = tid & 63;
    int q = lane & 31, b = lane >> 5;
    int bid = blockIdx.x;
    int bb = bid & 7;                    // batch -> XCD pinned
    int qt = bid >> 3;
    int n0 = qt * 128;
    int row128 = w * 32 + q;
    size_t qrow = ((size_t)bb * 4096 + n0 + row128) * 128;

    f16x8 Qf[8];
#pragma unroll
    for (int ks = 0; ks < 8; ks++)
        Qf[ks] = *(const f16x8*)&th[qrow + ks * 16 + b * 8];

    float mrow = -INFINITY, lrow = 0.f;
    f32x16 o[4];
#pragma unroll
    for (int c = 0; c < 4; c++) o[c] = (f32x16)0.f;

    // staging assignment (reg-prefetch): phi 64x128 -> 4 chunks/thread;
    // g 128x64 -> 4 chunks/thread
    int prow = tid >> 2, pchk = (tid & 3) * 4;
    int grow = tid >> 1, gchk = (tid & 1) * 4;
    const size_t gtb = (size_t)bb * (128 * 2048) + (size_t)grow * 2048;

    s16x8 cph[4], cg[4];
#pragma unroll
    for (int c = 0; c < 4; c++) {        // prologue: tile 0
        cph[c] = *(const s16x8*)&ph[(((size_t)(bb * 2048 + prow)) << 7) + (pchk + c) * 8];
        cg[c]  = *(const s16x8*)&gt[gtb + (gchk + c) * 8];
    }

    for (int kt = 0; kt < 32; kt++) {
        // regs -> LDS (swizzled writes)
#pragma unroll
        for (int c = 0; c < 4; c++) {
            *(s16x8*)&skh[(prow << 7) + (((pchk + c) ^ (prow & 7)) << 3)] = cph[c];
            *(s16x8*)&sg[(grow << 6) + (((gchk + c) ^ (grow & 7)) << 3)] = cg[c];
        }
        __syncthreads();

        // prefetch tile kt+1 into regs -- lands under the compute below
        s16x8 nph[4], ng[4];
        if (kt + 1 < 32) {
            int m1 = (kt + 1) * 64;
#pragma unroll
            for (int c = 0; c < 4; c++) {
                nph[c] = *(const s16x8*)&ph[(((size_t)(bb * 2048 + m1 + prow)) << 7) + (pchk + c) * 8];
                ng[c]  = *(const s16x8*)&gt[gtb + m1 + (gchk + c) * 8];
            }
        }

        // S^T = phi . theta^T : single fp16 pass. D[key][query], col = q
        f32x16 S[2];
        S[0] = (f32x16)0.f; S[1] = (f32x16)0.f;
        __builtin_amdgcn_s_setprio(1);
#pragma unroll
        for (int ks = 0; ks < 8; ks++) {
            int off0 = (q << 7) + (((ks * 2 + b) ^ (q & 7)) << 3);
            int r1 = 32 + q;
            int off1 = (r1 << 7) + (((ks * 2 + b) ^ (r1 & 7)) << 3);
            f16x8 a0 = *(const f16x8*)&skh[off0];
            f16x8 a1 = *(const f16x8*)&skh[off1];
            S[0] = MFMA32F(a0, Qf[ks], S[0]);
            S[1] = MFMA32F(a1, Qf[ks], S[1]);
        }
        __builtin_amdgcn_s_setprio(0);

        // tree max (depth 5) + cross-half shuffle
        float t0[8];
#pragma unroll
        for (int r = 0; r < 8; r++)
            t0[r] = fmaxf(fmaxf(S[0][r], S[0][r + 8]),
                          fmaxf(S[1][r], S[1][r + 8]));
        float u0 = fmaxf(t0[0], t0[1]), u1 = fmaxf(t0[2], t0[3]);
        float u2 = fmaxf(t0[4], t0[5]), u3 = fmaxf(t0[6], t0[7]);
        float vmax = fmaxf(fmaxf(u0, u1), fmaxf(u2, u3));
        vmax = fmaxf(vmax, __shfl_xor(vmax, 32, 64));

        // deferred rescale (THR=20: P <= e^20, l <= 2048*e^20 -- f32 safe)
        if (!__all(vmax - mrow <= 20.f)) {
            float nm = fmaxf(mrow, vmax);
            float alph = __expf(mrow - nm);
            mrow = nm;
            lrow *= alph;
#pragma unroll
            for (int c = 0; c < 4; c++)
#pragma unroll
                for (int r = 0; r < 16; r++) o[c][r] *= alph;
        }
        float rs0 = 0.f, rs1 = 0.f, rs2 = 0.f, rs3 = 0.f;
#pragma unroll
        for (int r = 0; r < 4; r++) {
            float p00 = __expf(S[0][r] - mrow);      S[0][r] = p00;      rs0 += p00;
            float p01 = __expf(S[0][r + 4] - mrow);  S[0][r + 4] = p01;  rs1 += p01;
            float p02 = __expf(S[0][r + 8] - mrow);  S[0][r + 8] = p02;  rs2 += p02;
            float p03 = __expf(S[0][r + 12] - mrow); S[0][r + 12] = p03; rs3 += p03;
            float p10 = __expf(S[1][r] - mrow);      S[1][r] = p10;      rs0 += p10;
            float p11 = __expf(S[1][r + 4] - mrow);  S[1][r + 4] = p11;  rs1 += p11;
            float p12 = __expf(S[1][r + 8] - mrow);  S[1][r + 8] = p12;  rs2 += p12;
            float p13 = __expf(S[1][r + 12] - mrow); S[1][r + 12] = p13; rs3 += p13;
        }
        float rs = (rs0 + rs1) + (rs2 + rs3);
        rs += __shfl_xor(rs, 32, 64);
        lrow += rs;

        // P @ V: B-fragments packed straight from S D-regs (no LDS!)
        __builtin_amdgcn_s_setprio(1);
#pragma unroll
        for (int t = 0; t < 4; t++) {
            int half = t >> 1, base = (t & 1) * 8;
            s16x8 Pf;
            u32* pf = (u32*)&Pf;
#pragma unroll
            for (int r2 = 0; r2 < 4; r2++)
                pf[r2] = pkbf(S[half][base + 2 * r2], S[half][base + 2 * r2 + 1]);
#pragma unroll
            for (int c = 0; c < 4; c++) {
                int ch = c * 32 + q;
                int off = (ch << 6) + (((t * 2 + b) ^ (ch & 7)) << 3);
                s16x8 gv = *(const s16x8*)&sg[off];
                o[c] = MFMA32(gv, Pf, o[c]);
            }
        }
        __builtin_amdgcn_s_setprio(0);

        // all waves done reading skh/sg before next tile's writes
        __syncthreads();
        if (kt + 1 < 32) {
#pragma unroll
            for (int c = 0; c < 4; c++) { cph[c] = nph[c]; cg[c] = ng[c]; }
        }
    }

    // ---- fused epilogue: normalize O, stage to LDS, W_out GEMM + residual
    u16* sy = smem;                      // 128 rows x 128 ch bf16, swz
    u16* sw = smem + 16384;              // 128 outcol x 128 ch bf16, swz
    float inv = 1.f / lrow;              // exact: full key range in this block
#pragma unroll
    for (int c = 0; c < 4; c++)
#pragma unroll
        for (int r2 = 0; r2 < 8; r2++) {
            int ch = c * 32 + ((r2 & 1) << 1) + 8 * (r2 >> 1) + 4 * b;
            u32 pk = pkbf(o[c][2 * r2] * inv, o[c][2 * r2 + 1] * inv);
            int chunk = (ch >> 3) ^ (row128 & 7);
            *(u32*)&sy[(row128 << 7) + (chunk << 3) + (ch & 7)] = pk;
        }

    int wr = (w >> 1) * 64, wc = (w & 1) * 64, li = lane & 15, qq = lane >> 4;
    int wrow = tid >> 1;
#pragma unroll
    for (int half = 0; half < 2; half++) {
        int c0 = half * 128;
        __syncthreads();                 // sy complete / previous half done
#pragma unroll
        for (int c = 0; c < 8; c++) {    // stage wot half: 128 B/thread
            int chunk = (tid & 1) * 8 + c;
            *(s16x8*)&sw[(wrow << 7) + ((chunk ^ (wrow & 7)) << 3)] =
                *(const s16x8*)&wot[(size_t)(c0 + wrow) * 128 + chunk * 8];
        }
        __syncthreads();

        f32x4 acc[4][4];
#pragma unroll
        for (int i = 0; i < 4; i++)
#pragma unroll
            for (int j = 0; j < 4; j++) acc[i][j] = (f32x4)0.f;

#pragma unroll
        for (int ks = 0; ks < 4; ks++) {
            s16x8 av[4], bv[4];
#pragma unroll
            for (int i = 0; i < 4; i++) {
                int ar = wr + i * 16 + li;
                av[i] = *(const s16x8*)&sy[(ar << 7) + ((((ks * 4 + qq)) ^ (ar & 7)) << 3)];
                int br = wc + i * 16 + li;
                bv[i] = *(const s16x8*)&sw[(br << 7) + ((((ks * 4 + qq)) ^ (br & 7)) << 3)];
            }
#pragma unroll
            for (int i = 0; i < 4; i++)
#pragma unroll
                for (int j = 0; j < 4; j++)
                    acc[i][j] = MFMA(av[i], bv[j], acc[i][j]);
        }

        // direct store: D row = qq*4+reg (16-tile), col = li -> 64B runs
#pragma unroll
        for (int i = 0; i < 4; i++)
#pragma unroll
            for (int j = 0; j < 4; j++)
#pragma unroll
                for (int reg = 0; reg < 4; reg++) {
                    size_t grow_ = (size_t)bb * 4096 + n0 + wr + i * 16 + qq * 4 + reg;
                    int gcol = c0 + wc + j * 16 + li;
                    out[grow_ * 256 + gcol] = x[grow_ * 256 + gcol] + acc[i][j][reg];
                }
    }
}

// ---------------------------------------------------------------- launch
extern "C" void kernel_launch(void* const* d_in, const int* in_sizes, int n_in,
                              void* d_out, int out_size, void* d_ws, size_t ws_size,
                              hipStream_t stream) {
    const float* x  = (const float*)d_in[0];
    const float* wt = (const float*)d_in[1];
    const float* wp = (const float*)d_in[2];
    const float* wg = (const float*)d_in[3];
    const float* wo = (const float*)d_in[4];
    float* out = (float*)d_out;

    char* p = (char*)d_ws;
    auto alloc = [&](size_t bytes) {
        char* r = p;
        p += (bytes + 255) & ~(size_t)255;
        return r;
    };
    const size_t NT = (size_t)BB * NN * CBD;   // 4194304
    const size_t NP = (size_t)BB * MM * CBD;   // 2097152

    u16* wtf = (u16*)alloc(CC * CBD * 2);      // fp16 W_theta^T
    u16* wpf = (u16*)alloc(CC * CBD * 2);      // fp16 W_phi^T
    u16* wgf = (u16*)alloc(CC * CBD * 2);      // fp16 W_g^T
    u16* wot = (u16*)alloc(CC * CBD * 2);      // bf16 W_out^T
    u16* th  = (u16*)alloc(NT * 2);            // fp16 theta
    u16* ph  = (u16*)alloc(NP * 2);            // fp16 pooled phi
    u16* gt  = (u16*)alloc(NP * 2);            // bf16 pooled g (PV perm)

    k_split_w<<<dim3(128, 4), 256, 0, stream>>>(wt, wp, wg, wo,
                                                wtf, wpf, wgf, wot);
    k_proj<<<dim3(512), 256, 0, stream>>>(x, wtf, wpf, wgf, th, ph, gt);
    k_attn<<<dim3(256), 256, 0, stream>>>(th, ph, gt, wot, x, out);
}